// Round 10
// baseline (192.532 us; speedup 1.0000x reference)
//
#include <hip/hip_runtime.h>
#include <hip/hip_bf16.h>

#define LJ 256008       // T*BANDS
#define TN 32001
#define OUT_LEN 32000

__device__ __forceinline__ int swz(int u) { return u ^ (((u >> 4) & 7) << 2); }

// ---------------- h1 = relu(x @ lstm_W1 + b1), stored [i][b] (f32) ----------------
__global__ __launch_bounds__(256) void k_h1(const float* __restrict__ x,
                                            const float* __restrict__ W1,
                                            const float* __restrict__ b1,
                                            float* __restrict__ h1)
{
    int idx = blockIdx.x * 256 + threadIdx.x;   // 4096 outputs
    if (idx >= 4096) return;
    int b = idx >> 6, i = idx & 63;
    float acc = b1[i];
    #pragma unroll
    for (int f = 0; f < 16; ++f)
        acc += x[b * 16 + f] * W1[f * 64 + i];
    h1[i * 64 + b] = fmaxf(acc, 0.f);
}

// ---- big GEMM: edc_pred = h1 @ W2 + b2 (f32 out) + fused band-mean edc1d + fused t-sums -------
__global__ __launch_bounds__(256) void k_gemm(const float* __restrict__ W2,
                                              const float* __restrict__ b2,
                                              const float* __restrict__ h1,
                                              float* __restrict__ edc,
                                              float* __restrict__ edc1d,
                                              float* __restrict__ sums)
{
    __shared__ float h1s[4096];
    int tid = threadIdx.x;
    for (int r = tid; r < 4096; r += 256) h1s[r] = h1[r];
    __syncthreads();
    int lane = tid & 63, bg = tid >> 6;          // wave-uniform bg
    long jb = (long)blockIdx.x * 256 + lane;     // this thread's columns: jb + 64*c
    float acc[4][16];
    #pragma unroll
    for (int c = 0; c < 4; ++c)
        #pragma unroll
        for (int b = 0; b < 16; ++b) acc[c][b] = 0.f;
    bool a0 = jb < LJ, a1 = jb + 64 < LJ, a2 = jb + 128 < LJ, a3 = jb + 192 < LJ;
    for (int i = 0; i < 64; ++i) {
        const float* wr = W2 + (long)i * LJ + jb;
        float w0 = a0 ? wr[0]   : 0.f;
        float w1 = a1 ? wr[64]  : 0.f;
        float w2 = a2 ? wr[128] : 0.f;
        float w3 = a3 ? wr[192] : 0.f;
        const float4* hv = (const float4*)(h1s + i * 64 + bg * 16);
        #pragma unroll
        for (int b4 = 0; b4 < 4; ++b4) {
            float4 h4 = hv[b4];
            acc[0][b4*4+0] += h4.x * w0; acc[0][b4*4+1] += h4.y * w0;
            acc[0][b4*4+2] += h4.z * w0; acc[0][b4*4+3] += h4.w * w0;
            acc[1][b4*4+0] += h4.x * w1; acc[1][b4*4+1] += h4.y * w1;
            acc[1][b4*4+2] += h4.z * w1; acc[1][b4*4+3] += h4.w * w1;
            acc[2][b4*4+0] += h4.x * w2; acc[2][b4*4+1] += h4.y * w2;
            acc[2][b4*4+2] += h4.z * w2; acc[2][b4*4+3] += h4.w * w2;
            acc[3][b4*4+0] += h4.x * w3; acc[3][b4*4+1] += h4.y * w3;
            acc[3][b4*4+2] += h4.z * w3; acc[3][b4*4+3] += h4.w * w3;
        }
    }
    int bgbase = bg * 16;
    float myA[16];
    #pragma unroll
    for (int b = 0; b < 16; ++b) myA[b] = 0.f;
    #pragma unroll
    for (int c = 0; c < 4; ++c) {
        long j = jb + 64 * c;
        if (j < LJ) {               // 8-lane groups never split here (LJ % 8 == 0)
            float bias = b2[j];
            int t = (int)(j >> 3), band = (int)(j & 7);
            #pragma unroll
            for (int b = 0; b < 16; ++b) {
                float v = acc[c][b] + bias;
                edc[(long)(bgbase + b) * LJ + j] = v;
                myA[b] += v;
                float s = v;
                s += __shfl_xor(s, 1);
                s += __shfl_xor(s, 2);
                s += __shfl_xor(s, 4);
                if (band == 0) edc1d[(long)(bgbase + b) * TN + t] = s * 0.125f;
            }
        }
    }
    // reduce myA over the 8 lanes sharing (band = lane&7) within this wave
    #pragma unroll
    for (int b = 0; b < 16; ++b) {
        myA[b] += __shfl_xor(myA[b], 8);
        myA[b] += __shfl_xor(myA[b], 16);
        myA[b] += __shfl_xor(myA[b], 32);
    }
    if (lane < 8) {
        int band = lane;
        bool inQ1 = (blockIdx.x < 250);    // t < 8000  <=> j < 64000
        bool inQ4 = (blockIdx.x >= 750);   // t >= 24000 <=> j >= 192000
        #pragma unroll
        for (int b = 0; b < 16; ++b) {
            float v = myA[b];
            float* base = sums + (bgbase + b) * 24 + band * 3;
            atomicAdd(base + 0, v);
            if (inQ1) atomicAdd(base + 1, v);
            if (inQ4) atomicAdd(base + 2, v);
        }
    }
}

// ---------------- small MLP head: one block per batch row, f32 outputs ----------------
__global__ __launch_bounds__(64) void k_mlp(const float* __restrict__ x,
    const float* __restrict__ sums,
    const float* __restrict__ eW1, const float* __restrict__ eb1,
    const float* __restrict__ eW2, const float* __restrict__ eb2,
    const float* __restrict__ dW1, const float* __restrict__ db1,
    const float* __restrict__ dW2, const float* __restrict__ db2,
    const float* __restrict__ aW1, const float* __restrict__ ab1,
    const float* __restrict__ aW2, const float* __restrict__ ab2,
    const float* __restrict__ bW1, const float* __restrict__ bb1,
    const float* __restrict__ bW2, const float* __restrict__ bb2,
    float* __restrict__ out_lk, float* __restrict__ out_a, float* __restrict__ out_b)
{
    int b = blockIdx.x, o = threadIdx.x;
    __shared__ float feat[16], a1[64], hh[64], t1[64];
    if (o < 16) {
        float v;
        if (o < 8) v = sums[b * 24 + o * 3] * (1.f / 32001.f);
        else {
            int band = o - 8;
            v = sums[b * 24 + band * 3 + 2] * (1.f / 8001.f)
              - sums[b * 24 + band * 3 + 1] * (1.f / 8000.f);
        }
        feat[o] = v;
    }
    __syncthreads();
    {   float acc = eb1[o];
        #pragma unroll
        for (int c = 0; c < 16; ++c) acc += feat[c] * eW1[c * 64 + o];
        a1[o] = fmaxf(acc, 0.f); }
    __syncthreads();
    {   float acc = eb2[o];
        for (int c = 0; c < 64; ++c) acc += a1[c] * eW2[c * 64 + o];
        hh[o] = fmaxf(acc, 0.f); }
    __syncthreads();
    {   float acc = db1[o];
        #pragma unroll
        for (int c = 0; c < 3; ++c) acc += x[b * 16 + c] * dW1[c * 64 + o];
        for (int c = 0; c < 64; ++c) acc += hh[c] * dW1[(3 + c) * 64 + o];
        t1[o] = fmaxf(acc, 0.f); }
    __syncthreads();
    if (o < 16) {
        float acc = db2[o];
        for (int c = 0; c < 64; ++c) acc += t1[c] * dW2[c * 16 + o];
        out_lk[b * 16 + o] = acc;
    }
    __syncthreads();
    if (o < 32) {
        float acc = ab1[o];
        for (int c = 0; c < 64; ++c) acc += hh[c] * aW1[c * 32 + o];
        t1[o] = fmaxf(acc, 0.f);
    }
    __syncthreads();
    if (o < 16) {
        float acc = ab2[o];
        for (int c = 0; c < 32; ++c) acc += t1[c] * aW2[c * 16 + o];
        out_a[b * 16 + o] = acc;
    }
    __syncthreads();
    if (o < 32) {
        float acc = bb1[o];
        for (int c = 0; c < 64; ++c) acc += hh[c] * bW1[c * 32 + o];
        t1[o] = fmaxf(acc, 0.f);
    }
    __syncthreads();
    if (o < 16) {
        float acc = bb2[o];
        for (int c = 0; c < 32; ++c) acc += t1[c] * bW2[c * 16 + o];
        out_b[b * 16 + o] = acc;
    }
}

// ---------------- parity stage 1: packed bits (per-(b, 256-chunk) inclusive XOR scan) ----------
__global__ __launch_bounds__(256) void k_par1(const int* __restrict__ flips,
                                              unsigned* __restrict__ parbits,
                                              unsigned* __restrict__ ctot)
{
    int b = blockIdx.x, c = blockIdx.y, tid = threadIdx.x;
    int t = c * 256 + tid;
    int bit = (t == 0) ? 0 : (flips[(long)b * OUT_LEN + t] & 1);
    int lane = tid & 63, wv = tid >> 6;
    unsigned long long mask = __ballot(bit != 0);
    int below = ((int)__popcll(mask & ((1ull << lane) - 1ull))) & 1;
    int incl = below ^ bit;
    __shared__ int wtot[4];
    if (lane == 0) wtot[wv] = ((int)__popcll(mask)) & 1;
    __syncthreads();
    int pre = 0;
    for (int w = 0; w < wv; ++w) pre ^= wtot[w];
    int inclB = pre ^ incl;
    unsigned long long m2 = __ballot(inclB != 0);
    if (lane == 0)  parbits[b * 1000 + c * 8 + wv * 2 + 0] = (unsigned)(m2 & 0xffffffffull);
    if (lane == 32) parbits[b * 1000 + c * 8 + wv * 2 + 1] = (unsigned)(m2 >> 32);
    if (tid == 0) ctot[c * 64 + b] = (unsigned)(wtot[0] ^ wtot[1] ^ wtot[2] ^ wtot[3]);
}

// ---------------- parity stage 2: exclusive prefix over chunks ----------------
__global__ __launch_bounds__(64) void k_par2(const unsigned* __restrict__ ctot,
                                             unsigned* __restrict__ cpref)
{
    int b = threadIdx.x;
    unsigned carry = 0;
    for (int c = 0; c < 125; ++c) {
        cpref[c * 64 + b] = carry;
        carry ^= ctot[c * 64 + b];
    }
}

// ------- conv (late+early) + amp + sign -> rir; swizzled LDS, 8 outputs/thread, 4 waves/SIMD ---
__global__ __launch_bounds__(256) void k_conv(const float* __restrict__ edc1d,
    const float* __restrict__ lk, const float* __restrict__ eg,
    const unsigned* __restrict__ parbits, const unsigned* __restrict__ cpref,
    float* __restrict__ rir)
{
    __shared__ __align__(16) float ker[1024];
    __shared__ __align__(16) float sw[3104];     // 3073 used; swizzle permutes within 32-float wins
    int b = blockIdx.x, t0 = blockIdx.y * 2048, tid = threadIdx.x;
    for (int k = tid; k < 1024; k += 256) {
        float g = lk[k];
        if (k < 43) g += eg[k];                   // early+late = one conv
        ker[k] = g;
    }
    const float* src = edc1d + (long)b * TN;
    for (int u = tid; u < 3073; u += 256) {
        int gt = t0 - 1024 + u;
        float v = (gt >= 0 && gt <= OUT_LEN) ? src[gt] : 0.f;
        sw[swz(u)] = v;
    }
    __syncthreads();
    int lt = tid * 8;
    int t = t0 + lt;
    if (t >= OUT_LEN) return;
    float acc[8];
    #pragma unroll
    for (int d = 0; d < 8; ++d) acc[d] = 0.f;
    for (int k16 = 0; k16 < 1024; k16 += 16) {
        const float4* gp = (const float4*)(ker + k16);
        float4 g0 = gp[0], g1 = gp[1], g2 = gp[2], g3 = gp[3];
        float g[16] = {g0.x,g0.y,g0.z,g0.w, g1.x,g1.y,g1.z,g1.w,
                       g2.x,g2.y,g2.z,g2.w, g3.x,g3.y,g3.z,g3.w};
        int ch0 = (lt + 1024 - k16 - 16) >> 2;    // base chunk (24 floats = 6 chunks)
        float w2[24];
        #pragma unroll
        for (int s = 0; s < 6; ++s) {
            int a = ch0 + s;
            int as = a ^ ((a >> 2) & 7);          // chunk-level swizzle == swz on floats
            float4 v = *(const float4*)(sw + 4 * as);
            w2[4*s+0] = v.x; w2[4*s+1] = v.y; w2[4*s+2] = v.z; w2[4*s+3] = v.w;
        }
        #pragma unroll
        for (int j = 0; j < 16; ++j)
            #pragma unroll
            for (int d = 0; d < 8; ++d)
                acc[d] += g[j] * w2[16 + d - j];  // w2[m] = src[t - k16 - 16 + m]
    }
    float sv[9];
    #pragma unroll
    for (int d = 0; d < 9; ++d) sv[d] = sw[swz(lt + 1024 + d)];
    unsigned pw = parbits[b * 1000 + (t >> 5)];   // all 8 t share one word (t%32 in {0,8,16,24})
    unsigned cp = cpref[(t >> 8) * 64 + b] & 1u;
    int sh = t & 31;
    float r[8];
    #pragma unroll
    for (int d = 0; d < 8; ++d) {
        float diff = sv[d] - sv[d + 1];
        float amp = diff > 0.f ? sqrtf(diff) : 0.f;
        unsigned p = ((pw >> (sh + d)) & 1u) ^ cp;
        float sgn = p ? -1.f : 1.f;
        r[d] = acc[d] * amp * sgn;
    }
    float4* dst = (float4*)(rir + (long)b * OUT_LEN + t);
    dst[0] = make_float4(r[0], r[1], r[2], r[3]);
    dst[1] = make_float4(r[4], r[5], r[6], r[7]);
}

extern "C" void kernel_launch(void* const* d_in, const int* in_sizes, int n_in,
                              void* d_out, int out_size, void* d_ws, size_t ws_size,
                              hipStream_t stream) {
    (void)in_sizes; (void)n_in; (void)out_size; (void)ws_size;
    const float* x    = (const float*)d_in[0];
    const float* lW1  = (const float*)d_in[1];  const float* lb1 = (const float*)d_in[2];
    const float* lW2  = (const float*)d_in[3];  const float* lb2 = (const float*)d_in[4];
    const float* eW1  = (const float*)d_in[5];  const float* eb1 = (const float*)d_in[6];
    const float* eW2  = (const float*)d_in[7];  const float* eb2 = (const float*)d_in[8];
    const float* dW1  = (const float*)d_in[9];  const float* db1 = (const float*)d_in[10];
    const float* dW2  = (const float*)d_in[11]; const float* db2 = (const float*)d_in[12];
    const float* aW1  = (const float*)d_in[13]; const float* ab1 = (const float*)d_in[14];
    const float* aW2  = (const float*)d_in[15]; const float* ab2 = (const float*)d_in[16];
    const float* bW1  = (const float*)d_in[17]; const float* bb1 = (const float*)d_in[18];
    const float* bW2  = (const float*)d_in[19]; const float* bb2 = (const float*)d_in[20];
    const float* eg   = (const float*)d_in[21]; const float* lkk = (const float*)d_in[22];
    const int* flips  = (const int*)d_in[23];

    float* out = (float*)d_out;                    // f32 output buffer
    float* rir = out;                              // 2,048,000
    float* edc = out + 2048000;                    // 16,384,512
    float* olk = out + 18432512;                   // 1,024
    float* oa  = out + 18433536;                   // 1,024
    float* ob  = out + 18434560;                   // 1,024

    // -------- compact ws layout (total 8,538,368 B) --------
    char* wsb = (char*)d_ws;
    float*    ws_h1   = (float*)(wsb + 1024);       // 16,384 B
    unsigned* ws_ct   = (unsigned*)(wsb + 18432);   // 32,000 B
    unsigned* ws_cp   = (unsigned*)(wsb + 50688);   // 32,000 B
    unsigned* ws_pb   = (unsigned*)(wsb + 82944);   // 256,000 B
    float*    ws_sums = (float*)(wsb + 339200);     // 6,144 B
    float*    ws_e1d  = (float*)(wsb + 346112);     // 8,192,256 B -> ends 8,538,368

    hipMemsetAsync(ws_sums, 0, 64 * 24 * sizeof(float), stream);

    k_h1<<<16, 256, 0, stream>>>(x, lW1, lb1, ws_h1);
    k_par1<<<dim3(64, 125), 256, 0, stream>>>(flips, ws_pb, ws_ct);
    k_par2<<<1, 64, 0, stream>>>(ws_ct, ws_cp);
    k_gemm<<<1001, 256, 0, stream>>>(lW2, lb2, ws_h1, edc, ws_e1d, ws_sums);
    k_mlp<<<64, 64, 0, stream>>>(x, ws_sums, eW1, eb1, eW2, eb2, dW1, db1, dW2, db2,
                                 aW1, ab1, aW2, ab2, bW1, bb1, bW2, bb2, olk, oa, ob);
    k_conv<<<dim3(64, 16), 256, 0, stream>>>(ws_e1d, lkk, eg, ws_pb, ws_cp, rir);
}

// Round 11
// 147.606 us; speedup vs baseline: 1.3044x; 1.3044x over previous
//
#include <hip/hip_runtime.h>
#include <hip/hip_bf16.h>

#define LJ 256008       // T*BANDS
#define TN 32001
#define OUT_LEN 32000

__device__ __forceinline__ int swz(int u) { return u ^ (((u >> 4) & 7) << 2); }

// ---------------- h1 = relu(x @ lstm_W1 + b1), stored [i][b] (f32) ----------------
__global__ __launch_bounds__(256) void k_h1(const float* __restrict__ x,
                                            const float* __restrict__ W1,
                                            const float* __restrict__ b1,
                                            float* __restrict__ h1)
{
    int idx = blockIdx.x * 256 + threadIdx.x;   // 4096 outputs
    if (idx >= 4096) return;
    int b = idx >> 6, i = idx & 63;
    float acc = b1[i];
    #pragma unroll
    for (int f = 0; f < 16; ++f)
        acc += x[b * 16 + f] * W1[f * 64 + i];
    h1[i * 64 + b] = fmaxf(acc, 0.f);
}

// ---- big GEMM: edc_pred = h1 @ W2 + b2 (float4 I/O) + fused band-mean -> edc1d ----------------
// wave w handles batch group [16w,16w+16); lane l handles 4 consecutive cols jb4 = blk*256+4l.
__global__ __launch_bounds__(256) void k_gemm(const float* __restrict__ W2,
                                              const float* __restrict__ b2,
                                              const float* __restrict__ h1,
                                              float* __restrict__ edc,
                                              float* __restrict__ edc1d)
{
    __shared__ float h1s[4096];
    int tid = threadIdx.x;
    for (int r = tid; r < 4096; r += 256) h1s[r] = h1[r];
    __syncthreads();
    int lane = tid & 63, bg = tid >> 6;            // wave-uniform bg
    long jb4 = (long)blockIdx.x * 256 + 4 * lane;  // this lane's float4 of columns
    bool ok = jb4 < LJ;                            // LJ%4==0 -> whole float4 valid
    float acc[16][4];
    #pragma unroll
    for (int b = 0; b < 16; ++b)
        #pragma unroll
        for (int c = 0; c < 4; ++c) acc[b][c] = 0.f;
    for (int i = 0; i < 64; ++i) {
        float4 w = ok ? *(const float4*)(W2 + (long)i * LJ + jb4)
                      : make_float4(0.f, 0.f, 0.f, 0.f);
        const float4* hv = (const float4*)(h1s + i * 64 + bg * 16);
        #pragma unroll
        for (int b4 = 0; b4 < 4; ++b4) {
            float4 h4 = hv[b4];
            acc[b4*4+0][0] += h4.x * w.x; acc[b4*4+0][1] += h4.x * w.y;
            acc[b4*4+0][2] += h4.x * w.z; acc[b4*4+0][3] += h4.x * w.w;
            acc[b4*4+1][0] += h4.y * w.x; acc[b4*4+1][1] += h4.y * w.y;
            acc[b4*4+1][2] += h4.y * w.z; acc[b4*4+1][3] += h4.y * w.w;
            acc[b4*4+2][0] += h4.z * w.x; acc[b4*4+2][1] += h4.z * w.y;
            acc[b4*4+2][2] += h4.z * w.z; acc[b4*4+2][3] += h4.z * w.w;
            acc[b4*4+3][0] += h4.w * w.x; acc[b4*4+3][1] += h4.w * w.y;
            acc[b4*4+3][2] += h4.w * w.z; acc[b4*4+3][3] += h4.w * w.w;
        }
    }
    if (!ok) return;
    int bgbase = bg * 16;
    float4 bias = *(const float4*)(b2 + jb4);
    int tcol = (int)(jb4 >> 3);                    // same t for the whole float4
    #pragma unroll
    for (int b = 0; b < 16; ++b) {
        float4 v = make_float4(acc[b][0] + bias.x, acc[b][1] + bias.y,
                               acc[b][2] + bias.z, acc[b][3] + bias.w);
        *(float4*)(edc + (long)(bgbase + b) * LJ + jb4) = v;
        float s = v.x + v.y + v.z + v.w;           // half of the 8-col band group
        s += __shfl_xor(s, 1);                     // partner lane holds the other half
        if ((lane & 1) == 0)
            edc1d[(long)(bgbase + b) * TN + tcol] = s * 0.125f;
    }
}

// ---------------- time/quartile means of edc_pred -> sums[b][band][{all,q1,q4}] ----------------
__global__ __launch_bounds__(256) void k_reduce(const float* __restrict__ edc,
                                                float* __restrict__ sums)
{
    int b = blockIdx.x, c = blockIdx.y, tid = threadIdx.x;
    float sA = 0.f, s1 = 0.f, s4 = 0.f;
    const float* row = edc + (long)b * LJ;
    for (int it = 0; it < 8; ++it) {
        int jl = c * 8192 + (tid + it * 256) * 4;     // 4-aligned -> single t per float4
        if (jl < LJ) {
            float4 v = *(const float4*)(row + jl);
            float s = v.x + v.y + v.z + v.w;
            int t = jl >> 3;
            sA += s;
            if (t < 8000) s1 += s;
            if (t >= 24000) s4 += s;
        }
    }
    __shared__ float red[768];
    red[tid] = sA; red[tid + 256] = s1; red[tid + 512] = s4;
    __syncthreads();
    #pragma unroll
    for (int off = 128; off >= 8; off >>= 1) {
        if (tid < off) {
            red[tid] += red[tid + off];
            red[tid + 256] += red[tid + 256 + off];
            red[tid + 512] += red[tid + 512 + off];
        }
        __syncthreads();
    }
    if (tid < 8) {
        atomicAdd(&sums[b * 24 + tid * 3 + 0], red[tid]);
        atomicAdd(&sums[b * 24 + tid * 3 + 1], red[tid + 256]);
        atomicAdd(&sums[b * 24 + tid * 3 + 2], red[tid + 512]);
    }
}

// ---------------- small MLP head: one block per batch row, f32 outputs ----------------
__global__ __launch_bounds__(64) void k_mlp(const float* __restrict__ x,
    const float* __restrict__ sums,
    const float* __restrict__ eW1, const float* __restrict__ eb1,
    const float* __restrict__ eW2, const float* __restrict__ eb2,
    const float* __restrict__ dW1, const float* __restrict__ db1,
    const float* __restrict__ dW2, const float* __restrict__ db2,
    const float* __restrict__ aW1, const float* __restrict__ ab1,
    const float* __restrict__ aW2, const float* __restrict__ ab2,
    const float* __restrict__ bW1, const float* __restrict__ bb1,
    const float* __restrict__ bW2, const float* __restrict__ bb2,
    float* __restrict__ out_lk, float* __restrict__ out_a, float* __restrict__ out_b)
{
    int b = blockIdx.x, o = threadIdx.x;
    __shared__ float feat[16], a1[64], hh[64], t1[64];
    if (o < 16) {
        float v;
        if (o < 8) v = sums[b * 24 + o * 3] * (1.f / 32001.f);
        else {
            int band = o - 8;
            v = sums[b * 24 + band * 3 + 2] * (1.f / 8001.f)
              - sums[b * 24 + band * 3 + 1] * (1.f / 8000.f);
        }
        feat[o] = v;
    }
    __syncthreads();
    {   float acc = eb1[o];
        #pragma unroll
        for (int c = 0; c < 16; ++c) acc += feat[c] * eW1[c * 64 + o];
        a1[o] = fmaxf(acc, 0.f); }
    __syncthreads();
    {   float acc = eb2[o];
        for (int c = 0; c < 64; ++c) acc += a1[c] * eW2[c * 64 + o];
        hh[o] = fmaxf(acc, 0.f); }
    __syncthreads();
    {   float acc = db1[o];
        #pragma unroll
        for (int c = 0; c < 3; ++c) acc += x[b * 16 + c] * dW1[c * 64 + o];
        for (int c = 0; c < 64; ++c) acc += hh[c] * dW1[(3 + c) * 64 + o];
        t1[o] = fmaxf(acc, 0.f); }
    __syncthreads();
    if (o < 16) {
        float acc = db2[o];
        for (int c = 0; c < 64; ++c) acc += t1[c] * dW2[c * 16 + o];
        out_lk[b * 16 + o] = acc;
    }
    __syncthreads();
    if (o < 32) {
        float acc = ab1[o];
        for (int c = 0; c < 64; ++c) acc += hh[c] * aW1[c * 32 + o];
        t1[o] = fmaxf(acc, 0.f);
    }
    __syncthreads();
    if (o < 16) {
        float acc = ab2[o];
        for (int c = 0; c < 32; ++c) acc += t1[c] * aW2[c * 16 + o];
        out_a[b * 16 + o] = acc;
    }
    __syncthreads();
    if (o < 32) {
        float acc = bb1[o];
        for (int c = 0; c < 64; ++c) acc += hh[c] * bW1[c * 32 + o];
        t1[o] = fmaxf(acc, 0.f);
    }
    __syncthreads();
    if (o < 16) {
        float acc = bb2[o];
        for (int c = 0; c < 32; ++c) acc += t1[c] * bW2[c * 16 + o];
        out_b[b * 16 + o] = acc;
    }
}

// ---------------- parity stage 1: packed bits (per-(b, 256-chunk) inclusive XOR scan) ----------
__global__ __launch_bounds__(256) void k_par1(const int* __restrict__ flips,
                                              unsigned* __restrict__ parbits,
                                              unsigned* __restrict__ ctot)
{
    int b = blockIdx.x, c = blockIdx.y, tid = threadIdx.x;
    int t = c * 256 + tid;
    int bit = (t == 0) ? 0 : (flips[(long)b * OUT_LEN + t] & 1);
    int lane = tid & 63, wv = tid >> 6;
    unsigned long long mask = __ballot(bit != 0);
    int below = ((int)__popcll(mask & ((1ull << lane) - 1ull))) & 1;
    int incl = below ^ bit;
    __shared__ int wtot[4];
    if (lane == 0) wtot[wv] = ((int)__popcll(mask)) & 1;
    __syncthreads();
    int pre = 0;
    for (int w = 0; w < wv; ++w) pre ^= wtot[w];
    int inclB = pre ^ incl;
    unsigned long long m2 = __ballot(inclB != 0);
    if (lane == 0)  parbits[b * 1000 + c * 8 + wv * 2 + 0] = (unsigned)(m2 & 0xffffffffull);
    if (lane == 32) parbits[b * 1000 + c * 8 + wv * 2 + 1] = (unsigned)(m2 >> 32);
    if (tid == 0) ctot[c * 64 + b] = (unsigned)(wtot[0] ^ wtot[1] ^ wtot[2] ^ wtot[3]);
}

// ---------------- parity stage 2: exclusive prefix over chunks ----------------
__global__ __launch_bounds__(64) void k_par2(const unsigned* __restrict__ ctot,
                                             unsigned* __restrict__ cpref)
{
    int b = threadIdx.x;
    unsigned carry = 0;
    for (int c = 0; c < 125; ++c) {
        cpref[c * 64 + b] = carry;
        carry ^= ctot[c * 64 + b];
    }
}

// ------- conv (late+early) + amp + sign -> rir; swizzled LDS, 8 outputs/thread ----------------
__global__ __launch_bounds__(256) void k_conv(const float* __restrict__ edc1d,
    const float* __restrict__ lk, const float* __restrict__ eg,
    const unsigned* __restrict__ parbits, const unsigned* __restrict__ cpref,
    float* __restrict__ rir)
{
    __shared__ __align__(16) float ker[1024];
    __shared__ __align__(16) float sw[3104];     // 3073 used; swizzle permutes within 32-float wins
    int b = blockIdx.x, t0 = blockIdx.y * 2048, tid = threadIdx.x;
    for (int k = tid; k < 1024; k += 256) {
        float g = lk[k];
        if (k < 43) g += eg[k];                   // early+late = one conv
        ker[k] = g;
    }
    const float* src = edc1d + (long)b * TN;
    for (int u = tid; u < 3073; u += 256) {
        int gt = t0 - 1024 + u;
        float v = (gt >= 0 && gt <= OUT_LEN) ? src[gt] : 0.f;
        sw[swz(u)] = v;
    }
    __syncthreads();
    int lt = tid * 8;
    int t = t0 + lt;
    if (t >= OUT_LEN) return;
    float acc[8];
    #pragma unroll
    for (int d = 0; d < 8; ++d) acc[d] = 0.f;
    for (int k16 = 0; k16 < 1024; k16 += 16) {
        const float4* gp = (const float4*)(ker + k16);
        float4 g0 = gp[0], g1 = gp[1], g2 = gp[2], g3 = gp[3];
        float g[16] = {g0.x,g0.y,g0.z,g0.w, g1.x,g1.y,g1.z,g1.w,
                       g2.x,g2.y,g2.z,g2.w, g3.x,g3.y,g3.z,g3.w};
        int ch0 = (lt + 1024 - k16 - 16) >> 2;    // base chunk (24 floats = 6 chunks)
        float w2[24];
        #pragma unroll
        for (int s = 0; s < 6; ++s) {
            int a = ch0 + s;
            int as = a ^ ((a >> 2) & 7);          // chunk-level swizzle == swz on floats
            float4 v = *(const float4*)(sw + 4 * as);
            w2[4*s+0] = v.x; w2[4*s+1] = v.y; w2[4*s+2] = v.z; w2[4*s+3] = v.w;
        }
        #pragma unroll
        for (int j = 0; j < 16; ++j)
            #pragma unroll
            for (int d = 0; d < 8; ++d)
                acc[d] += g[j] * w2[16 + d - j];  // w2[m] = src[t - k16 - 16 + m]
    }
    float sv[9];
    #pragma unroll
    for (int d = 0; d < 9; ++d) sv[d] = sw[swz(lt + 1024 + d)];
    unsigned pw = parbits[b * 1000 + (t >> 5)];   // all 8 t share one word (t%32 in {0,8,16,24})
    unsigned cp = cpref[(t >> 8) * 64 + b] & 1u;
    int sh = t & 31;
    float r[8];
    #pragma unroll
    for (int d = 0; d < 8; ++d) {
        float diff = sv[d] - sv[d + 1];
        float amp = diff > 0.f ? sqrtf(diff) : 0.f;
        unsigned p = ((pw >> (sh + d)) & 1u) ^ cp;
        float sgn = p ? -1.f : 1.f;
        r[d] = acc[d] * amp * sgn;
    }
    float4* dst = (float4*)(rir + (long)b * OUT_LEN + t);
    dst[0] = make_float4(r[0], r[1], r[2], r[3]);
    dst[1] = make_float4(r[4], r[5], r[6], r[7]);
}

extern "C" void kernel_launch(void* const* d_in, const int* in_sizes, int n_in,
                              void* d_out, int out_size, void* d_ws, size_t ws_size,
                              hipStream_t stream) {
    (void)in_sizes; (void)n_in; (void)out_size; (void)ws_size;
    const float* x    = (const float*)d_in[0];
    const float* lW1  = (const float*)d_in[1];  const float* lb1 = (const float*)d_in[2];
    const float* lW2  = (const float*)d_in[3];  const float* lb2 = (const float*)d_in[4];
    const float* eW1  = (const float*)d_in[5];  const float* eb1 = (const float*)d_in[6];
    const float* eW2  = (const float*)d_in[7];  const float* eb2 = (const float*)d_in[8];
    const float* dW1  = (const float*)d_in[9];  const float* db1 = (const float*)d_in[10];
    const float* dW2  = (const float*)d_in[11]; const float* db2 = (const float*)d_in[12];
    const float* aW1  = (const float*)d_in[13]; const float* ab1 = (const float*)d_in[14];
    const float* aW2  = (const float*)d_in[15]; const float* ab2 = (const float*)d_in[16];
    const float* bW1  = (const float*)d_in[17]; const float* bb1 = (const float*)d_in[18];
    const float* bW2  = (const float*)d_in[19]; const float* bb2 = (const float*)d_in[20];
    const float* eg   = (const float*)d_in[21]; const float* lkk = (const float*)d_in[22];
    const int* flips  = (const int*)d_in[23];

    float* out = (float*)d_out;                    // f32 output buffer
    float* rir = out;                              // 2,048,000
    float* edc = out + 2048000;                    // 16,384,512
    float* olk = out + 18432512;                   // 1,024
    float* oa  = out + 18433536;                   // 1,024
    float* ob  = out + 18434560;                   // 1,024

    // -------- compact ws layout (total 8,538,368 B) --------
    char* wsb = (char*)d_ws;
    float*    ws_h1   = (float*)(wsb + 1024);       // 16,384 B
    unsigned* ws_ct   = (unsigned*)(wsb + 18432);   // 32,000 B
    unsigned* ws_cp   = (unsigned*)(wsb + 50688);   // 32,000 B
    unsigned* ws_pb   = (unsigned*)(wsb + 82944);   // 256,000 B
    float*    ws_sums = (float*)(wsb + 339200);     // 6,144 B
    float*    ws_e1d  = (float*)(wsb + 346112);     // 8,192,256 B -> ends 8,538,368

    hipMemsetAsync(ws_sums, 0, 64 * 24 * sizeof(float), stream);

    k_h1<<<16, 256, 0, stream>>>(x, lW1, lb1, ws_h1);
    k_par1<<<dim3(64, 125), 256, 0, stream>>>(flips, ws_pb, ws_ct);
    k_par2<<<1, 64, 0, stream>>>(ws_ct, ws_cp);
    k_gemm<<<1001, 256, 0, stream>>>(lW2, lb2, ws_h1, edc, ws_e1d);
    k_reduce<<<dim3(64, 32), 256, 0, stream>>>(edc, ws_sums);
    k_mlp<<<64, 64, 0, stream>>>(x, ws_sums, eW1, eb1, eW2, eb2, dW1, db1, dW2, db2,
                                 aW1, ab1, aW2, ab2, bW1, bb1, bW2, bb2, olk, oa, ob);
    k_conv<<<dim3(64, 16), 256, 0, stream>>>(ws_e1d, lkk, eg, ws_pb, ws_cp, rir);
}

// Round 12
// 107.224 us; speedup vs baseline: 1.7956x; 1.3766x over previous
//
#include <hip/hip_runtime.h>
#include <hip/hip_bf16.h>

#define LJ 256008       // T*BANDS
#define TN 32001
#define OUT_LEN 32000

typedef __attribute__((ext_vector_type(8))) short short8v;
typedef __attribute__((ext_vector_type(8))) __bf16 bf16x8;
typedef __attribute__((ext_vector_type(4))) float f32x4;

__device__ __forceinline__ unsigned short f2bu(float f) {
    union { __hip_bfloat16 h; unsigned short u; } cv; cv.h = __float2bfloat16(f); return cv.u;
}

// ---------------- h1 = relu(x @ lstm_W1 + b1), stored [i][b] (f32) ----------------
__global__ __launch_bounds__(256) void k_h1(const float* __restrict__ x,
                                            const float* __restrict__ W1,
                                            const float* __restrict__ b1,
                                            float* __restrict__ h1)
{
    int idx = blockIdx.x * 256 + threadIdx.x;   // 4096 outputs
    if (idx >= 4096) return;
    int b = idx >> 6, i = idx & 63;
    float acc = b1[i];
    #pragma unroll
    for (int f = 0; f < 16; ++f)
        acc += x[b * 16 + f] * W1[f * 64 + i];
    h1[i * 64 + b] = fmaxf(acc, 0.f);
}

// ---- big GEMM: edc_pred = h1 @ W2 + b2 (float4 I/O) + fused band-mean edc1d + band partials ----
__global__ __launch_bounds__(256) void k_gemm(const float* __restrict__ W2,
                                              const float* __restrict__ b2,
                                              const float* __restrict__ h1,
                                              float* __restrict__ edc,
                                              float* __restrict__ edc1d,
                                              float* __restrict__ P)
{
    __shared__ float h1s[4096];
    int tid = threadIdx.x;
    for (int r = tid; r < 4096; r += 256) h1s[r] = h1[r];
    __syncthreads();
    int lane = tid & 63, bg = tid >> 6;            // wave-uniform bg
    long jb4 = (long)blockIdx.x * 256 + 4 * lane;  // this lane's float4 of columns
    bool ok = jb4 < LJ;                            // LJ%4==0 -> whole float4 valid
    float acc[16][4];
    #pragma unroll
    for (int b = 0; b < 16; ++b)
        #pragma unroll
        for (int c = 0; c < 4; ++c) acc[b][c] = 0.f;
    for (int i = 0; i < 64; ++i) {
        float4 w = ok ? *(const float4*)(W2 + (long)i * LJ + jb4)
                      : make_float4(0.f, 0.f, 0.f, 0.f);
        const float4* hv = (const float4*)(h1s + i * 64 + bg * 16);
        #pragma unroll
        for (int b4 = 0; b4 < 4; ++b4) {
            float4 h4 = hv[b4];
            acc[b4*4+0][0] += h4.x * w.x; acc[b4*4+0][1] += h4.x * w.y;
            acc[b4*4+0][2] += h4.x * w.z; acc[b4*4+0][3] += h4.x * w.w;
            acc[b4*4+1][0] += h4.y * w.x; acc[b4*4+1][1] += h4.y * w.y;
            acc[b4*4+1][2] += h4.y * w.z; acc[b4*4+1][3] += h4.y * w.w;
            acc[b4*4+2][0] += h4.z * w.x; acc[b4*4+2][1] += h4.z * w.y;
            acc[b4*4+2][2] += h4.z * w.z; acc[b4*4+2][3] += h4.z * w.w;
            acc[b4*4+3][0] += h4.w * w.x; acc[b4*4+3][1] += h4.w * w.y;
            acc[b4*4+3][2] += h4.w * w.z; acc[b4*4+3][3] += h4.w * w.w;
        }
    }
    int bgbase = bg * 16;
    float4 bias = ok ? *(const float4*)(b2 + jb4) : make_float4(0.f, 0.f, 0.f, 0.f);
    int tcol = (int)(jb4 >> 3);                    // same t for the whole float4
    #pragma unroll
    for (int b = 0; b < 16; ++b) {
        float r0, r1, r2, r3;
        if (ok) {
            float4 v = make_float4(acc[b][0] + bias.x, acc[b][1] + bias.y,
                                   acc[b][2] + bias.z, acc[b][3] + bias.w);
            *(float4*)(edc + (long)(bgbase + b) * LJ + jb4) = v;
            float s = v.x + v.y + v.z + v.w;       // half of the 8-col band group
            s += __shfl_xor(s, 1);                 // partner lane has the other half
            if ((lane & 1) == 0)
                edc1d[(long)(bgbase + b) * TN + tcol] = s * 0.125f;
            r0 = v.x; r1 = v.y; r2 = v.z; r3 = v.w;
        } else { r0 = r1 = r2 = r3 = 0.f; }
        // reduce over same-parity lanes (band = 4*(lane&1)+e)
        r0 += __shfl_xor(r0, 2);  r1 += __shfl_xor(r1, 2);
        r2 += __shfl_xor(r2, 2);  r3 += __shfl_xor(r3, 2);
        r0 += __shfl_xor(r0, 4);  r1 += __shfl_xor(r1, 4);
        r2 += __shfl_xor(r2, 4);  r3 += __shfl_xor(r3, 4);
        r0 += __shfl_xor(r0, 8);  r1 += __shfl_xor(r1, 8);
        r2 += __shfl_xor(r2, 8);  r3 += __shfl_xor(r3, 8);
        r0 += __shfl_xor(r0, 16); r1 += __shfl_xor(r1, 16);
        r2 += __shfl_xor(r2, 16); r3 += __shfl_xor(r3, 16);
        r0 += __shfl_xor(r0, 32); r1 += __shfl_xor(r1, 32);
        r2 += __shfl_xor(r2, 32); r3 += __shfl_xor(r3, 32);
        if (lane < 2)
            *(float4*)(P + (long)blockIdx.x * 512 + (bgbase + b) * 8 + lane * 4)
                = make_float4(r0, r1, r2, r3);
    }
}

// ---------------- sum block partials -> sums[b][band][{all,q1,q4}] ----------------
__global__ __launch_bounds__(512) void k_redsum(const float* __restrict__ P,
                                                float* __restrict__ sums)
{
    int g = blockIdx.x, t = threadIdx.x;           // t = batch*8 + band
    int b = t >> 3, band = t & 7;
    int s0 = g * 16, s1 = s0 + 16;
    if (s1 > 1001) s1 = 1001;
    float all = 0.f, q1 = 0.f, q4 = 0.f;
    for (int blk = s0; blk < s1; ++blk) {
        float v = P[(long)blk * 512 + t];
        all += v;
        if (blk < 250) q1 += v;                    // t < 8000  <=> j < 64000
        if (blk >= 750) q4 += v;                   // t >= 24000 <=> j >= 192000
    }
    atomicAdd(&sums[b * 24 + band * 3 + 0], all);
    atomicAdd(&sums[b * 24 + band * 3 + 1], q1);
    atomicAdd(&sums[b * 24 + band * 3 + 2], q4);
}

// ---------------- small MLP head: one block per batch row, f32 outputs ----------------
__global__ __launch_bounds__(64) void k_mlp(const float* __restrict__ x,
    const float* __restrict__ sums,
    const float* __restrict__ eW1, const float* __restrict__ eb1,
    const float* __restrict__ eW2, const float* __restrict__ eb2,
    const float* __restrict__ dW1, const float* __restrict__ db1,
    const float* __restrict__ dW2, const float* __restrict__ db2,
    const float* __restrict__ aW1, const float* __restrict__ ab1,
    const float* __restrict__ aW2, const float* __restrict__ ab2,
    const float* __restrict__ bW1, const float* __restrict__ bb1,
    const float* __restrict__ bW2, const float* __restrict__ bb2,
    float* __restrict__ out_lk, float* __restrict__ out_a, float* __restrict__ out_b)
{
    int b = blockIdx.x, o = threadIdx.x;
    __shared__ float feat[16], a1[64], hh[64], t1[64];
    if (o < 16) {
        float v;
        if (o < 8) v = sums[b * 24 + o * 3] * (1.f / 32001.f);
        else {
            int band = o - 8;
            v = sums[b * 24 + band * 3 + 2] * (1.f / 8001.f)
              - sums[b * 24 + band * 3 + 1] * (1.f / 8000.f);
        }
        feat[o] = v;
    }
    __syncthreads();
    {   float acc = eb1[o];
        #pragma unroll
        for (int c = 0; c < 16; ++c) acc += feat[c] * eW1[c * 64 + o];
        a1[o] = fmaxf(acc, 0.f); }
    __syncthreads();
    {   float acc = eb2[o];
        for (int c = 0; c < 64; ++c) acc += a1[c] * eW2[c * 64 + o];
        hh[o] = fmaxf(acc, 0.f); }
    __syncthreads();
    {   float acc = db1[o];
        #pragma unroll
        for (int c = 0; c < 3; ++c) acc += x[b * 16 + c] * dW1[c * 64 + o];
        for (int c = 0; c < 64; ++c) acc += hh[c] * dW1[(3 + c) * 64 + o];
        t1[o] = fmaxf(acc, 0.f); }
    __syncthreads();
    if (o < 16) {
        float acc = db2[o];
        for (int c = 0; c < 64; ++c) acc += t1[c] * dW2[c * 16 + o];
        out_lk[b * 16 + o] = acc;
    }
    __syncthreads();
    if (o < 32) {
        float acc = ab1[o];
        for (int c = 0; c < 64; ++c) acc += hh[c] * aW1[c * 32 + o];
        t1[o] = fmaxf(acc, 0.f);
    }
    __syncthreads();
    if (o < 16) {
        float acc = ab2[o];
        for (int c = 0; c < 32; ++c) acc += t1[c] * aW2[c * 16 + o];
        out_a[b * 16 + o] = acc;
    }
    __syncthreads();
    if (o < 32) {
        float acc = bb1[o];
        for (int c = 0; c < 64; ++c) acc += hh[c] * bW1[c * 32 + o];
        t1[o] = fmaxf(acc, 0.f);
    }
    __syncthreads();
    if (o < 16) {
        float acc = bb2[o];
        for (int c = 0; c < 32; ++c) acc += t1[c] * bW2[c * 16 + o];
        out_b[b * 16 + o] = acc;
    }
}

// ---------------- parity stage 1: packed bits (per-(b, 256-chunk) inclusive XOR scan) ----------
__global__ __launch_bounds__(256) void k_par1(const int* __restrict__ flips,
                                              unsigned* __restrict__ parbits,
                                              unsigned* __restrict__ ctot)
{
    int b = blockIdx.x, c = blockIdx.y, tid = threadIdx.x;
    int t = c * 256 + tid;
    int bit = (t == 0) ? 0 : (flips[(long)b * OUT_LEN + t] & 1);
    int lane = tid & 63, wv = tid >> 6;
    unsigned long long mask = __ballot(bit != 0);
    int below = ((int)__popcll(mask & ((1ull << lane) - 1ull))) & 1;
    int incl = below ^ bit;
    __shared__ int wtot[4];
    if (lane == 0) wtot[wv] = ((int)__popcll(mask)) & 1;
    __syncthreads();
    int pre = 0;
    for (int w = 0; w < wv; ++w) pre ^= wtot[w];
    int inclB = pre ^ incl;
    unsigned long long m2 = __ballot(inclB != 0);
    if (lane == 0)  parbits[b * 1000 + c * 8 + wv * 2 + 0] = (unsigned)(m2 & 0xffffffffull);
    if (lane == 32) parbits[b * 1000 + c * 8 + wv * 2 + 1] = (unsigned)(m2 >> 32);
    if (tid == 0) ctot[c * 64 + b] = (unsigned)(wtot[0] ^ wtot[1] ^ wtot[2] ^ wtot[3]);
}

// ---------------- parity stage 2: exclusive prefix over chunks ----------------
__global__ __launch_bounds__(64) void k_par2(const unsigned* __restrict__ ctot,
                                             unsigned* __restrict__ cpref)
{
    int b = threadIdx.x;
    unsigned carry = 0;
    for (int c = 0; c < 125; ++c) {
        cpref[c * 64 + b] = carry;
        carry ^= ctot[c * 64 + b];
    }
}

// ------- MFMA Toeplitz conv (late+early) + amp + sign -> rir ----------------------------------
// C[r][c] = out[tb+16c+r] = sum_kb A_kb[r][m] * B_kb[m][c];  A = kernel Toeplitz (bf16, LDS
// per-lane-packed), B = bf16 signal window chunk (XOR-swizzled).  amp from separate f32 window.
__global__ __launch_bounds__(512) void k_convm(const float* __restrict__ edc1d,
    const float* __restrict__ lk, const float* __restrict__ eg,
    const unsigned* __restrict__ parbits, const unsigned* __restrict__ cpref,
    float* __restrict__ rir)
{
    __shared__ float kerf[1024];
    __shared__ __align__(16) unsigned short afr[33 * 64 * 8];  // A frags [kb][lane][e]
    __shared__ __align__(16) unsigned short sbf[3136];         // swizzled bf16 window
    __shared__ float sf32[2049];
    int b = blockIdx.x, tb0 = blockIdx.y * 2048, tid = threadIdx.x;
    const float* src = edc1d + (long)b * TN;
    // stage combined kernel taps (f32)
    for (int k = tid; k < 1024; k += 512)
        kerf[k] = lk[k] + (k < 43 ? eg[k] : 0.f);
    // stage bf16 window, 8-elem chunks, chunk-XOR-swizzled: u in [0,3104), gt = tb0 + u - 1031
    for (int ch = tid; ch < 388; ch += 512) {
        unsigned short h[8];
        #pragma unroll
        for (int e = 0; e < 8; ++e) {
            int gt = tb0 + ch * 8 + e - 1031;
            float v = (gt >= 0 && gt <= OUT_LEN) ? src[gt] : 0.f;
            h[e] = f2bu(v);
        }
        int cs = ch ^ ((ch >> 3) & 7);
        *(uint4*)(&sbf[cs * 8]) = make_uint4(
            (unsigned)h[0] | ((unsigned)h[1] << 16), (unsigned)h[2] | ((unsigned)h[3] << 16),
            (unsigned)h[4] | ((unsigned)h[5] << 16), (unsigned)h[6] | ((unsigned)h[7] << 16));
    }
    // stage f32 center window for amp
    for (int u = tid; u < 2049; u += 512) {
        int gt = tb0 + u;
        sf32[u] = (gt <= OUT_LEN) ? src[gt] : 0.f;
    }
    __syncthreads();
    // build A fragments: lane l holds A[l&15][8*(l>>4)+e] = g[K0+31+r-m], K0 = 32kb-32
    for (int sl = tid; sl < 33 * 64; sl += 512) {
        int kb = sl >> 6, l = sl & 63;
        int x0 = kb * 32 - 1 + (l & 15) - 8 * (l >> 4);    // x = x0 - e
        unsigned short h[8];
        #pragma unroll
        for (int e = 0; e < 8; ++e) {
            int x = x0 - e;
            float v = (x >= 0 && x < 1024) ? kerf[x] : 0.f;
            h[e] = f2bu(v);
        }
        *(uint4*)(&afr[sl * 8]) = make_uint4(
            (unsigned)h[0] | ((unsigned)h[1] << 16), (unsigned)h[2] | ((unsigned)h[3] << 16),
            (unsigned)h[4] | ((unsigned)h[5] << 16), (unsigned)h[6] | ((unsigned)h[7] << 16));
    }
    __syncthreads();
    int lane = tid & 63, wv = tid >> 6;                    // 8 waves, 1 C-tile each
    int tb = tb0 + wv * 256;
    int cq = wv * 256 + 16 * (lane & 15) + 8 * (lane >> 4) + 1032;  // B chunk base (kb=0)
    f32x4 acc = {0.f, 0.f, 0.f, 0.f};
    for (int kb = 0; kb < 33; ++kb) {
        short8v araw = *(const short8v*)(&afr[(kb * 64 + lane) * 8]);
        int ch = (cq - (kb << 5)) >> 3;
        int cs = ch ^ ((ch >> 3) & 7);
        short8v braw = *(const short8v*)(&sbf[cs * 8]);
        union { short8v s; bf16x8 v; } ua, ub2;
        ua.s = araw; ub2.s = braw;
        acc = __builtin_amdgcn_mfma_f32_16x16x32_bf16(ua.v, ub2.v, acc, 0, 0, 0);
    }
    // epilogue: lane holds rows 4q..4q+3 of col c -> 4 consecutive t
    int c = lane & 15, q = lane >> 4;
    int t4 = tb + 16 * c + 4 * q;
    if (t4 < OUT_LEN) {
        int u0 = t4 - tb0;
        unsigned pw = parbits[b * 1000 + (t4 >> 5)];       // 4 bits same word (t4%4==0)
        unsigned cp = cpref[(t4 >> 8) * 64 + b] & 1u;
        int sh = t4 & 31;
        float sv[5];
        #pragma unroll
        for (int e = 0; e < 5; ++e) sv[e] = sf32[u0 + e];
        float r[4];
        #pragma unroll
        for (int reg = 0; reg < 4; ++reg) {
            float diff = sv[reg] - sv[reg + 1];
            float amp = diff > 0.f ? sqrtf(diff) : 0.f;
            unsigned p = ((pw >> (sh + reg)) & 1u) ^ cp;
            r[reg] = acc[reg] * amp * (p ? -1.f : 1.f);
        }
        *(float4*)(rir + (long)b * OUT_LEN + t4) = make_float4(r[0], r[1], r[2], r[3]);
    }
}

extern "C" void kernel_launch(void* const* d_in, const int* in_sizes, int n_in,
                              void* d_out, int out_size, void* d_ws, size_t ws_size,
                              hipStream_t stream) {
    (void)in_sizes; (void)n_in; (void)out_size; (void)ws_size;
    const float* x    = (const float*)d_in[0];
    const float* lW1  = (const float*)d_in[1];  const float* lb1 = (const float*)d_in[2];
    const float* lW2  = (const float*)d_in[3];  const float* lb2 = (const float*)d_in[4];
    const float* eW1  = (const float*)d_in[5];  const float* eb1 = (const float*)d_in[6];
    const float* eW2  = (const float*)d_in[7];  const float* eb2 = (const float*)d_in[8];
    const float* dW1  = (const float*)d_in[9];  const float* db1 = (const float*)d_in[10];
    const float* dW2  = (const float*)d_in[11]; const float* db2 = (const float*)d_in[12];
    const float* aW1  = (const float*)d_in[13]; const float* ab1 = (const float*)d_in[14];
    const float* aW2  = (const float*)d_in[15]; const float* ab2 = (const float*)d_in[16];
    const float* bW1  = (const float*)d_in[17]; const float* bb1 = (const float*)d_in[18];
    const float* bW2  = (const float*)d_in[19]; const float* bb2 = (const float*)d_in[20];
    const float* eg   = (const float*)d_in[21]; const float* lkk = (const float*)d_in[22];
    const int* flips  = (const int*)d_in[23];

    float* out = (float*)d_out;                    // f32 output buffer
    float* rir = out;                              // 2,048,000
    float* edc = out + 2048000;                    // 16,384,512
    float* olk = out + 18432512;                   // 1,024
    float* oa  = out + 18433536;                   // 1,024
    float* ob  = out + 18434560;                   // 1,024

    // -------- ws layout --------
    char* wsb = (char*)d_ws;
    float*    ws_h1   = (float*)(wsb + 1024);       // 16,384 B
    unsigned* ws_ct   = (unsigned*)(wsb + 18432);   // 32,000 B
    unsigned* ws_cp   = (unsigned*)(wsb + 50688);   // 32,000 B
    unsigned* ws_pb   = (unsigned*)(wsb + 82944);   // 256,000 B
    float*    ws_sums = (float*)(wsb + 339200);     // 6,144 B
    float*    ws_e1d  = (float*)(wsb + 346112);     // 8,192,256 B -> ends 8,538,368
    float*    ws_part = (float*)(wsb + 8538368);    // 1001*512*4 = 2,050,048 B

    hipMemsetAsync(ws_sums, 0, 64 * 24 * sizeof(float), stream);

    k_h1<<<16, 256, 0, stream>>>(x, lW1, lb1, ws_h1);
    k_par1<<<dim3(64, 125), 256, 0, stream>>>(flips, ws_pb, ws_ct);
    k_par2<<<1, 64, 0, stream>>>(ws_ct, ws_cp);
    k_gemm<<<1001, 256, 0, stream>>>(lW2, lb2, ws_h1, edc, ws_e1d, ws_part);
    k_redsum<<<63, 512, 0, stream>>>(ws_part, ws_sums);
    k_mlp<<<64, 64, 0, stream>>>(x, ws_sums, eW1, eb1, eW2, eb2, dW1, db1, dW2, db2,
                                 aW1, ab1, aW2, ab2, bW1, bb1, bW2, bb2, olk, oa, ob);
    k_convm<<<dim3(64, 16), 512, 0, stream>>>(ws_e1d, lkk, eg, ws_pb, ws_cp, rir);
}

// Round 13
// 105.761 us; speedup vs baseline: 1.8204x; 1.0138x over previous
//
#include <hip/hip_runtime.h>
#include <hip/hip_bf16.h>

#define LJ 256008       // T*BANDS
#define TN 32001
#define OUT_LEN 32000

typedef __attribute__((ext_vector_type(8))) short short8v;
typedef __attribute__((ext_vector_type(8))) __bf16 bf16x8;
typedef __attribute__((ext_vector_type(4))) float f32x4;

__device__ __forceinline__ unsigned short f2bu(float f) {
    union { __hip_bfloat16 h; unsigned short u; } cv; cv.h = __float2bfloat16(f); return cv.u;
}

// ---------------- h1 = relu(x @ lstm_W1 + b1), stored [i][b] (f32) ----------------
__global__ __launch_bounds__(256) void k_h1(const float* __restrict__ x,
                                            const float* __restrict__ W1,
                                            const float* __restrict__ b1,
                                            float* __restrict__ h1)
{
    int idx = blockIdx.x * 256 + threadIdx.x;   // 4096 outputs
    if (idx >= 4096) return;
    int b = idx >> 6, i = idx & 63;
    float acc = b1[i];
    #pragma unroll
    for (int f = 0; f < 16; ++f)
        acc += x[b * 16 + f] * W1[f * 64 + i];
    h1[i * 64 + b] = fmaxf(acc, 0.f);
}

// ---- big GEMM: 512 thr / 8 waves, wave owns 8 batches x 256 cols; float4 I/O; fused reductions -
__global__ __launch_bounds__(512, 4) void k_gemm(const float* __restrict__ W2,
                                                 const float* __restrict__ b2,
                                                 const float* __restrict__ h1,
                                                 float* __restrict__ edc,
                                                 float* __restrict__ edc1d,
                                                 float* __restrict__ P)
{
    __shared__ float h1s[4096];
    int tid = threadIdx.x;
    for (int r = tid; r < 4096; r += 512) h1s[r] = h1[r];
    __syncthreads();
    int lane = tid & 63, wv = tid >> 6;            // 8 waves
    int bstart = wv * 8;                           // this wave's 8 batches
    long jb4 = (long)blockIdx.x * 256 + 4 * lane;  // this lane's float4 of columns
    bool ok = jb4 < LJ;
    float acc[8][4];
    #pragma unroll
    for (int b = 0; b < 8; ++b)
        #pragma unroll
        for (int c = 0; c < 4; ++c) acc[b][c] = 0.f;
    for (int i = 0; i < 64; ++i) {
        float4 w = ok ? *(const float4*)(W2 + (long)i * LJ + jb4)
                      : make_float4(0.f, 0.f, 0.f, 0.f);
        const float4* hv = (const float4*)(h1s + i * 64 + bstart);
        #pragma unroll
        for (int b4 = 0; b4 < 2; ++b4) {
            float4 h4 = hv[b4];
            acc[b4*4+0][0] += h4.x * w.x; acc[b4*4+0][1] += h4.x * w.y;
            acc[b4*4+0][2] += h4.x * w.z; acc[b4*4+0][3] += h4.x * w.w;
            acc[b4*4+1][0] += h4.y * w.x; acc[b4*4+1][1] += h4.y * w.y;
            acc[b4*4+1][2] += h4.y * w.z; acc[b4*4+1][3] += h4.y * w.w;
            acc[b4*4+2][0] += h4.z * w.x; acc[b4*4+2][1] += h4.z * w.y;
            acc[b4*4+2][2] += h4.z * w.z; acc[b4*4+2][3] += h4.z * w.w;
            acc[b4*4+3][0] += h4.w * w.x; acc[b4*4+3][1] += h4.w * w.y;
            acc[b4*4+3][2] += h4.w * w.z; acc[b4*4+3][3] += h4.w * w.w;
        }
    }
    float4 bias = ok ? *(const float4*)(b2 + jb4) : make_float4(0.f, 0.f, 0.f, 0.f);
    int tcol = (int)(jb4 >> 3);                    // same t for the whole float4
    #pragma unroll
    for (int b = 0; b < 8; ++b) {
        int bb = bstart + b;
        float r0, r1, r2, r3;
        if (ok) {
            float4 v = make_float4(acc[b][0] + bias.x, acc[b][1] + bias.y,
                                   acc[b][2] + bias.z, acc[b][3] + bias.w);
            *(float4*)(edc + (long)bb * LJ + jb4) = v;
            float s = v.x + v.y + v.z + v.w;       // half of the 8-col band group
            s += __shfl_xor(s, 1);                 // partner lane has the other half
            if ((lane & 1) == 0)
                edc1d[(long)bb * TN + tcol] = s * 0.125f;
            r0 = v.x; r1 = v.y; r2 = v.z; r3 = v.w;
        } else { r0 = r1 = r2 = r3 = 0.f; }
        // reduce over same-parity lanes (band = 4*(lane&1)+e)
        r0 += __shfl_xor(r0, 2);  r1 += __shfl_xor(r1, 2);
        r2 += __shfl_xor(r2, 2);  r3 += __shfl_xor(r3, 2);
        r0 += __shfl_xor(r0, 4);  r1 += __shfl_xor(r1, 4);
        r2 += __shfl_xor(r2, 4);  r3 += __shfl_xor(r3, 4);
        r0 += __shfl_xor(r0, 8);  r1 += __shfl_xor(r1, 8);
        r2 += __shfl_xor(r2, 8);  r3 += __shfl_xor(r3, 8);
        r0 += __shfl_xor(r0, 16); r1 += __shfl_xor(r1, 16);
        r2 += __shfl_xor(r2, 16); r3 += __shfl_xor(r3, 16);
        r0 += __shfl_xor(r0, 32); r1 += __shfl_xor(r1, 32);
        r2 += __shfl_xor(r2, 32); r3 += __shfl_xor(r3, 32);
        if (lane < 2)
            *(float4*)(P + (long)blockIdx.x * 512 + bb * 8 + lane * 4)
                = make_float4(r0, r1, r2, r3);
    }
}

// ---------------- sum block partials -> sums[b][band][{all,q1,q4}] ----------------
__global__ __launch_bounds__(512) void k_redsum(const float* __restrict__ P,
                                                float* __restrict__ sums)
{
    int g = blockIdx.x, t = threadIdx.x;           // t = batch*8 + band
    int b = t >> 3, band = t & 7;
    int s0 = g * 16, s1 = s0 + 16;
    if (s1 > 1001) s1 = 1001;
    float all = 0.f, q1 = 0.f, q4 = 0.f;
    for (int blk = s0; blk < s1; ++blk) {
        float v = P[(long)blk * 512 + t];
        all += v;
        if (blk < 250) q1 += v;                    // t < 8000  <=> j < 64000
        if (blk >= 750) q4 += v;                   // t >= 24000 <=> j >= 192000
    }
    atomicAdd(&sums[b * 24 + band * 3 + 0], all);
    atomicAdd(&sums[b * 24 + band * 3 + 1], q1);
    atomicAdd(&sums[b * 24 + band * 3 + 2], q4);
}

// ---------------- small MLP head: one block per batch row, f32 outputs ----------------
__global__ __launch_bounds__(64) void k_mlp(const float* __restrict__ x,
    const float* __restrict__ sums,
    const float* __restrict__ eW1, const float* __restrict__ eb1,
    const float* __restrict__ eW2, const float* __restrict__ eb2,
    const float* __restrict__ dW1, const float* __restrict__ db1,
    const float* __restrict__ dW2, const float* __restrict__ db2,
    const float* __restrict__ aW1, const float* __restrict__ ab1,
    const float* __restrict__ aW2, const float* __restrict__ ab2,
    const float* __restrict__ bW1, const float* __restrict__ bb1,
    const float* __restrict__ bW2, const float* __restrict__ bb2,
    float* __restrict__ out_lk, float* __restrict__ out_a, float* __restrict__ out_b)
{
    int b = blockIdx.x, o = threadIdx.x;
    __shared__ float feat[16], a1[64], hh[64], t1[64];
    if (o < 16) {
        float v;
        if (o < 8) v = sums[b * 24 + o * 3] * (1.f / 32001.f);
        else {
            int band = o - 8;
            v = sums[b * 24 + band * 3 + 2] * (1.f / 8001.f)
              - sums[b * 24 + band * 3 + 1] * (1.f / 8000.f);
        }
        feat[o] = v;
    }
    __syncthreads();
    {   float acc = eb1[o];
        #pragma unroll
        for (int c = 0; c < 16; ++c) acc += feat[c] * eW1[c * 64 + o];
        a1[o] = fmaxf(acc, 0.f); }
    __syncthreads();
    {   float acc = eb2[o];
        for (int c = 0; c < 64; ++c) acc += a1[c] * eW2[c * 64 + o];
        hh[o] = fmaxf(acc, 0.f); }
    __syncthreads();
    {   float acc = db1[o];
        #pragma unroll
        for (int c = 0; c < 3; ++c) acc += x[b * 16 + c] * dW1[c * 64 + o];
        for (int c = 0; c < 64; ++c) acc += hh[c] * dW1[(3 + c) * 64 + o];
        t1[o] = fmaxf(acc, 0.f); }
    __syncthreads();
    if (o < 16) {
        float acc = db2[o];
        for (int c = 0; c < 64; ++c) acc += t1[c] * dW2[c * 16 + o];
        out_lk[b * 16 + o] = acc;
    }
    __syncthreads();
    if (o < 32) {
        float acc = ab1[o];
        for (int c = 0; c < 64; ++c) acc += hh[c] * aW1[c * 32 + o];
        t1[o] = fmaxf(acc, 0.f);
    }
    __syncthreads();
    if (o < 16) {
        float acc = ab2[o];
        for (int c = 0; c < 32; ++c) acc += t1[c] * aW2[c * 16 + o];
        out_a[b * 16 + o] = acc;
    }
    __syncthreads();
    if (o < 32) {
        float acc = bb1[o];
        for (int c = 0; c < 64; ++c) acc += hh[c] * bW1[c * 32 + o];
        t1[o] = fmaxf(acc, 0.f);
    }
    __syncthreads();
    if (o < 16) {
        float acc = bb2[o];
        for (int c = 0; c < 32; ++c) acc += t1[c] * bW2[c * 16 + o];
        out_b[b * 16 + o] = acc;
    }
}

// ---------------- parity stage 1: packed bits (per-(b, 256-chunk) inclusive XOR scan) ----------
__global__ __launch_bounds__(256) void k_par1(const int* __restrict__ flips,
                                              unsigned* __restrict__ parbits,
                                              unsigned* __restrict__ ctot)
{
    int b = blockIdx.x, c = blockIdx.y, tid = threadIdx.x;
    int t = c * 256 + tid;
    int bit = (t == 0) ? 0 : (flips[(long)b * OUT_LEN + t] & 1);
    int lane = tid & 63, wv = tid >> 6;
    unsigned long long mask = __ballot(bit != 0);
    int below = ((int)__popcll(mask & ((1ull << lane) - 1ull))) & 1;
    int incl = below ^ bit;
    __shared__ int wtot[4];
    if (lane == 0) wtot[wv] = ((int)__popcll(mask)) & 1;
    __syncthreads();
    int pre = 0;
    for (int w = 0; w < wv; ++w) pre ^= wtot[w];
    int inclB = pre ^ incl;
    unsigned long long m2 = __ballot(inclB != 0);
    if (lane == 0)  parbits[b * 1000 + c * 8 + wv * 2 + 0] = (unsigned)(m2 & 0xffffffffull);
    if (lane == 32) parbits[b * 1000 + c * 8 + wv * 2 + 1] = (unsigned)(m2 >> 32);
    if (tid == 0) ctot[c * 64 + b] = (unsigned)(wtot[0] ^ wtot[1] ^ wtot[2] ^ wtot[3]);
}

// ---------------- parity stage 2: exclusive prefix over chunks ----------------
__global__ __launch_bounds__(64) void k_par2(const unsigned* __restrict__ ctot,
                                             unsigned* __restrict__ cpref)
{
    int b = threadIdx.x;
    unsigned carry = 0;
    for (int c = 0; c < 125; ++c) {
        cpref[c * 64 + b] = carry;
        carry ^= ctot[c * 64 + b];
    }
}

// ------- MFMA Toeplitz conv (late+early) + amp + sign -> rir ----------------------------------
__global__ __launch_bounds__(512) void k_convm(const float* __restrict__ edc1d,
    const float* __restrict__ lk, const float* __restrict__ eg,
    const unsigned* __restrict__ parbits, const unsigned* __restrict__ cpref,
    float* __restrict__ rir)
{
    __shared__ float kerf[1024];
    __shared__ __align__(16) unsigned short afr[33 * 64 * 8];  // A frags [kb][lane][e]
    __shared__ __align__(16) unsigned short sbf[3136];         // swizzled bf16 window
    __shared__ float sf32[2049];
    int b = blockIdx.x, tb0 = blockIdx.y * 2048, tid = threadIdx.x;
    const float* src = edc1d + (long)b * TN;
    for (int k = tid; k < 1024; k += 512)
        kerf[k] = lk[k] + (k < 43 ? eg[k] : 0.f);
    for (int ch = tid; ch < 388; ch += 512) {
        unsigned short h[8];
        #pragma unroll
        for (int e = 0; e < 8; ++e) {
            int gt = tb0 + ch * 8 + e - 1031;
            float v = (gt >= 0 && gt <= OUT_LEN) ? src[gt] : 0.f;
            h[e] = f2bu(v);
        }
        int cs = ch ^ ((ch >> 3) & 7);
        *(uint4*)(&sbf[cs * 8]) = make_uint4(
            (unsigned)h[0] | ((unsigned)h[1] << 16), (unsigned)h[2] | ((unsigned)h[3] << 16),
            (unsigned)h[4] | ((unsigned)h[5] << 16), (unsigned)h[6] | ((unsigned)h[7] << 16));
    }
    for (int u = tid; u < 2049; u += 512) {
        int gt = tb0 + u;
        sf32[u] = (gt <= OUT_LEN) ? src[gt] : 0.f;
    }
    __syncthreads();
    for (int sl = tid; sl < 33 * 64; sl += 512) {
        int kb = sl >> 6, l = sl & 63;
        int x0 = kb * 32 - 1 + (l & 15) - 8 * (l >> 4);    // x = x0 - e
        unsigned short h[8];
        #pragma unroll
        for (int e = 0; e < 8; ++e) {
            int x = x0 - e;
            float v = (x >= 0 && x < 1024) ? kerf[x] : 0.f;
            h[e] = f2bu(v);
        }
        *(uint4*)(&afr[sl * 8]) = make_uint4(
            (unsigned)h[0] | ((unsigned)h[1] << 16), (unsigned)h[2] | ((unsigned)h[3] << 16),
            (unsigned)h[4] | ((unsigned)h[5] << 16), (unsigned)h[6] | ((unsigned)h[7] << 16));
    }
    __syncthreads();
    int lane = tid & 63, wv = tid >> 6;                    // 8 waves, 1 C-tile each
    int tb = tb0 + wv * 256;
    int cq = wv * 256 + 16 * (lane & 15) + 8 * (lane >> 4) + 1032;  // B chunk base (kb=0)
    f32x4 acc = {0.f, 0.f, 0.f, 0.f};
    for (int kb = 0; kb < 33; ++kb) {
        short8v araw = *(const short8v*)(&afr[(kb * 64 + lane) * 8]);
        int ch = (cq - (kb << 5)) >> 3;
        int cs = ch ^ ((ch >> 3) & 7);
        short8v braw = *(const short8v*)(&sbf[cs * 8]);
        union { short8v s; bf16x8 v; } ua, ub2;
        ua.s = araw; ub2.s = braw;
        acc = __builtin_amdgcn_mfma_f32_16x16x32_bf16(ua.v, ub2.v, acc, 0, 0, 0);
    }
    int c = lane & 15, q = lane >> 4;
    int t4 = tb + 16 * c + 4 * q;
    if (t4 < OUT_LEN) {
        int u0 = t4 - tb0;
        unsigned pw = parbits[b * 1000 + (t4 >> 5)];       // 4 bits same word (t4%4==0)
        unsigned cp = cpref[(t4 >> 8) * 64 + b] & 1u;
        int sh = t4 & 31;
        float sv[5];
        #pragma unroll
        for (int e = 0; e < 5; ++e) sv[e] = sf32[u0 + e];
        float r[4];
        #pragma unroll
        for (int reg = 0; reg < 4; ++reg) {
            float diff = sv[reg] - sv[reg + 1];
            float amp = diff > 0.f ? sqrtf(diff) : 0.f;
            unsigned p = ((pw >> (sh + reg)) & 1u) ^ cp;
            r[reg] = acc[reg] * amp * (p ? -1.f : 1.f);
        }
        *(float4*)(rir + (long)b * OUT_LEN + t4) = make_float4(r[0], r[1], r[2], r[3]);
    }
}

extern "C" void kernel_launch(void* const* d_in, const int* in_sizes, int n_in,
                              void* d_out, int out_size, void* d_ws, size_t ws_size,
                              hipStream_t stream) {
    (void)in_sizes; (void)n_in; (void)out_size; (void)ws_size;
    const float* x    = (const float*)d_in[0];
    const float* lW1  = (const float*)d_in[1];  const float* lb1 = (const float*)d_in[2];
    const float* lW2  = (const float*)d_in[3];  const float* lb2 = (const float*)d_in[4];
    const float* eW1  = (const float*)d_in[5];  const float* eb1 = (const float*)d_in[6];
    const float* eW2  = (const float*)d_in[7];  const float* eb2 = (const float*)d_in[8];
    const float* dW1  = (const float*)d_in[9];  const float* db1 = (const float*)d_in[10];
    const float* dW2  = (const float*)d_in[11]; const float* db2 = (const float*)d_in[12];
    const float* aW1  = (const float*)d_in[13]; const float* ab1 = (const float*)d_in[14];
    const float* aW2  = (const float*)d_in[15]; const float* ab2 = (const float*)d_in[16];
    const float* bW1  = (const float*)d_in[17]; const float* bb1 = (const float*)d_in[18];
    const float* bW2  = (const float*)d_in[19]; const float* bb2 = (const float*)d_in[20];
    const float* eg   = (const float*)d_in[21]; const float* lkk = (const float*)d_in[22];
    const int* flips  = (const int*)d_in[23];

    float* out = (float*)d_out;                    // f32 output buffer
    float* rir = out;                              // 2,048,000
    float* edc = out + 2048000;                    // 16,384,512
    float* olk = out + 18432512;                   // 1,024
    float* oa  = out + 18433536;                   // 1,024
    float* ob  = out + 18434560;                   // 1,024

    // -------- ws layout --------
    char* wsb = (char*)d_ws;
    float*    ws_h1   = (float*)(wsb + 1024);       // 16,384 B
    unsigned* ws_ct   = (unsigned*)(wsb + 18432);   // 32,000 B
    unsigned* ws_cp   = (unsigned*)(wsb + 50688);   // 32,000 B
    unsigned* ws_pb   = (unsigned*)(wsb + 82944);   // 256,000 B
    float*    ws_sums = (float*)(wsb + 339200);     // 6,144 B
    float*    ws_e1d  = (float*)(wsb + 346112);     // 8,192,256 B -> ends 8,538,368
    float*    ws_part = (float*)(wsb + 8538368);    // 1001*512*4 = 2,050,048 B

    hipMemsetAsync(ws_sums, 0, 64 * 24 * sizeof(float), stream);

    k_h1<<<16, 256, 0, stream>>>(x, lW1, lb1, ws_h1);
    k_par1<<<dim3(64, 125), 256, 0, stream>>>(flips, ws_pb, ws_ct);
    k_par2<<<1, 64, 0, stream>>>(ws_ct, ws_cp);
    k_gemm<<<1001, 512, 0, stream>>>(lW2, lb2, ws_h1, edc, ws_e1d, ws_part);
    k_redsum<<<63, 512, 0, stream>>>(ws_part, ws_sums);
    k_mlp<<<64, 64, 0, stream>>>(x, ws_sums, eW1, eb1, eW2, eb2, dW1, db1, dW2, db2,
                                 aW1, ab1, aW2, ab2, bW1, bb1, bW2, bb2, olk, oa, ob);
    k_convm<<<dim3(64, 16), 512, 0, stream>>>(ws_e1d, lkk, eg, ws_pb, ws_cp, rir);
}